// Round 1
// 405.615 us; speedup vs baseline: 1.0463x; 1.0463x over previous
//
#include <hip/hip_runtime.h>
#include <hip/hip_bf16.h>

typedef __bf16 bf16_t;
typedef __attribute__((ext_vector_type(8))) __bf16 bf16x8;
typedef __attribute__((ext_vector_type(4))) float f32x4;

#define MFMA16(a, b, c) __builtin_amdgcn_mfma_f32_16x16x32_bf16((a), (b), (c), 0, 0, 0)

__device__ __forceinline__ unsigned short f2bf(float f) {
    bf16_t b = (bf16_t)f;
    return __builtin_bit_cast(unsigned short, b);
}

__device__ __forceinline__ void gload16(const void* g, void* l) {
    __builtin_amdgcn_global_load_lds(
        (const __attribute__((address_space(1))) void*)g,
        (__attribute__((address_space(3))) void*)l,
        16, 0, 0);
}

// ---------- fp32 -> bf16 elementwise convert (for X) ----------
__global__ __launch_bounds__(256) void cvtx(const float* __restrict__ src,
                                            bf16_t* __restrict__ dst) {
    size_t i = ((size_t)blockIdx.x * 256 + threadIdx.x) * 8;
    f32x4 v0 = *(const f32x4*)(src + i);
    f32x4 v1 = *(const f32x4*)(src + i + 4);
    bf16x8 o;
    o[0] = (bf16_t)v0[0]; o[1] = (bf16_t)v0[1];
    o[2] = (bf16_t)v0[2]; o[3] = (bf16_t)v0[3];
    o[4] = (bf16_t)v1[0]; o[5] = (bf16_t)v1[1];
    o[6] = (bf16_t)v1[2]; o[7] = (bf16_t)v1[3];
    *(bf16x8*)(dst + i) = o;
}

// ---------- batched 64x64 transpose + fp32->bf16 convert ----------
__global__ __launch_bounds__(256) void transcvt64(const float* __restrict__ src,
                                                  unsigned short* __restrict__ dst,
                                                  int R, int C) {
    __shared__ __align__(16) unsigned short tile[64][66];
    size_t off = (size_t)blockIdx.z * R * C;
    const float* s = src + off;
    unsigned short* d = dst + off;
    int tr = blockIdx.y * 64, tc = blockIdx.x * 64;
    int tid = threadIdx.x;
    int lr = tid >> 4;
    int lc = (tid & 15) * 4;
#pragma unroll
    for (int p = 0; p < 4; ++p) {
        int r = p * 16 + lr;
        f32x4 v = *(const f32x4*)(s + (size_t)(tr + r) * C + tc + lc);
        tile[r][lc + 0] = f2bf(v[0]); tile[r][lc + 1] = f2bf(v[1]);
        tile[r][lc + 2] = f2bf(v[2]); tile[r][lc + 3] = f2bf(v[3]);
    }
    __syncthreads();
#pragma unroll
    for (int p = 0; p < 4; ++p) {
        int oc = p * 16 + lr;
        ushort4 v;
        v.x = tile[lc + 0][oc]; v.y = tile[lc + 1][oc];
        v.z = tile[lc + 2][oc]; v.w = tile[lc + 3][oc];
        *(ushort4*)(d + (size_t)(tc + oc) * R + tr + lc) = v;
    }
}

// =====================================================================
// 8-phase 256-row-tile GEMMs (T2+T3+T4+T5 stack, plain HIP).
//
// LDS staging layout per 16KB-or-8KB "stage" (one k-half of one operand):
//   line L (128B) holds rows {2L, 2L+1} x 4 chunks; slot sig (0..7):
//     row = 2L + (sig>>2), chunk-within-half = (sig&3) ^ (L&3)
//   global_load_lds dest is linear (base + idx*16B); the permutation lives
//   in the per-thread GLOBAL source offset and is inverted on ds_read.
//   Frag read (row, quad): sig = ((row&1)<<2) | (quad ^ ((row>>1)&3)),
//   elem = (row>>1)*64 + sig*8  -> conflict-free ds_read_b128.
// Phase skeleton (per guide §5): reads | stage-issue | counted vmcnt |
//   s_barrier | lgkmcnt(0) | setprio(1) 16xMFMA setprio(0) | s_barrier.
// =====================================================================

#define PH_FENCE { __builtin_amdgcn_sched_barrier(0); asm volatile("" ::: "memory"); }

// ---------- GEMM1 fused: Hh = silu(X*W1) * (X*W3) ----------
// Tile 256(M) x 128(N), BK=64, 8 waves = 4M x 2N, per-wave 64x64 per matrix.
__global__ __launch_bounds__(512, 2) void gemm13(const bf16_t* __restrict__ Xb,
                                                 const bf16_t* __restrict__ W1t,
                                                 const bf16_t* __restrict__ W3t,
                                                 bf16_t* __restrict__ Hh,
                                                 int row_base) {
    const int K = 1024, N = 2048, KT = 16;
    int nwg = gridDim.x, id = blockIdx.x;
    if ((nwg & 7) == 0) id = (id & 7) * (nwg >> 3) + (id >> 3);  // XCD swizzle
    int nbx = nwg >> 4;                    // 16 col-blocks
    int bx = id % nbx, by = id / nbx;      // col-major: XCD keeps W-panels in L2
    int row0 = bx * 256, col0 = by * 128;
    int seg = ((row_base + row0) & 2047) >> 9;
    const bf16_t* Ag  = Xb + (size_t)row0 * K;
    const bf16_t* B1g = W1t + ((size_t)seg * N + col0) * K;
    const bf16_t* B3g = W3t + ((size_t)seg * N + col0) * K;

    __shared__ __align__(16) bf16_t smem[65536];     // 128 KB
    bf16_t* sA  = smem;            // [d:2][ks:2][8192]  (256 rows x 32k / half)
    bf16_t* sB1 = smem + 32768;    // [d:2][ks:2][4096]  (128 rows x 32k / half)
    bf16_t* sB3 = smem + 49152;

    int tid = threadIdx.x, lane = tid & 63, w = tid >> 6;
    int wm = w >> 1, wn = w & 1;           // 4M x 2N
    int quad = lane >> 4, l16 = lane & 15;

    // per-thread staging constants (idx=tid covers 128 rows; +512 -> +128 rows)
    int r0 = 2 * (tid >> 3) + ((tid >> 2) & 1);
    int c0 = (tid & 3) ^ ((tid >> 3) & 3);
    int offG  = r0 * K + c0 * 8;
    int offG2 = offG + 128 * K;

    // per-lane read constants
    int sigRd = ((l16 & 1) << 2) | (quad ^ ((l16 >> 1) & 3));
    int rdA = (wm * 32 + (l16 >> 1)) * 64 + sigRd * 8;  // + i*512 (+ks*8192)
    int rdB = (wn * 32 + (l16 >> 1)) * 64 + sigRd * 8;  // + j*512 (+ks*4096)

    f32x4 accU[4][4], accV[4][4];
    f32x4 z = {0.f, 0.f, 0.f, 0.f};
#pragma unroll
    for (int i = 0; i < 4; ++i)
#pragma unroll
        for (int j = 0; j < 4; ++j) { accU[i][j] = z; accV[i][j] = z; }

    bf16x8 af0[4], af1[4], bfr[4];

#define STGA13(k0, dst) { gload16(Ag + (k0) + offG, (dst) + tid * 8); \
                          gload16(Ag + (k0) + offG2, (dst) + 4096 + tid * 8); }
#define STGB13(gb, k0, dst) { gload16((gb) + (k0) + offG, (dst) + tid * 8); }

#define PH13(d, ks, SBASE, AF, RDA, ACC, STAGE, WAITA) {                        \
    PH_FENCE;                                                                   \
    if (RDA) {                                                                  \
        _Pragma("unroll")                                                       \
        for (int i_ = 0; i_ < 4; ++i_)                                          \
            AF[i_] = *(const bf16x8*)(sA + (d) * 16384 + (ks) * 8192 + rdA + i_ * 512); \
    }                                                                           \
    _Pragma("unroll")                                                           \
    for (int j_ = 0; j_ < 4; ++j_)                                              \
        bfr[j_] = *(const bf16x8*)((SBASE) + (d) * 8192 + (ks) * 4096 + rdB + j_ * 512); \
    STAGE;                                                                      \
    WAITA;                                                                      \
    __builtin_amdgcn_s_barrier();                                               \
    asm volatile("s_waitcnt lgkmcnt(0)" ::: "memory");                          \
    __builtin_amdgcn_sched_barrier(0);                                          \
    __builtin_amdgcn_s_setprio(1);                                              \
    _Pragma("unroll")                                                           \
    for (int i_ = 0; i_ < 4; ++i_)                                              \
        _Pragma("unroll")                                                       \
        for (int j_ = 0; j_ < 4; ++j_)                                          \
            ACC[i_][j_] = MFMA16(AF[i_], bfr[j_], ACC[i_][j_]);                 \
    __builtin_amdgcn_s_setprio(0);                                              \
    __builtin_amdgcn_s_barrier();                                               \
}

// Stage order per tile: S0=A-k0(2 loads) S1=B1-k0(1) S2=A-k1(2) S3=B1-k1(1)
// S4=B3-k0(1) S5=B3-k1(1). Needs: p0:{S0,S1} p1:{S2,S3} p2:{S4} p3:{S5}.
// Counted waits (loads): C0=5 C1=7 C2=7 C3=5 — never 0 in the main loop.
#define TILE13(d, kn) {                                                         \
    PH13(d, 0, sB1, af0, 1, accU,                                               \
         { STGA13(kn, sA + (1 - (d)) * 16384);                                  \
           STGB13(B1g, kn, sB1 + (1 - (d)) * 8192); },                          \
         asm volatile("s_waitcnt vmcnt(5)" ::: "memory"));                      \
    PH13(d, 1, sB1, af1, 1, accU,                                               \
         { STGA13((kn) + 32, sA + (1 - (d)) * 16384 + 8192);                    \
           STGB13(B1g, (kn) + 32, sB1 + (1 - (d)) * 8192 + 4096); },            \
         asm volatile("s_waitcnt vmcnt(7)" ::: "memory"));                      \
    PH13(d, 0, sB3, af0, 0, accV,                                               \
         { STGB13(B3g, kn, sB3 + (1 - (d)) * 8192); },                          \
         asm volatile("s_waitcnt vmcnt(7)" ::: "memory"));                      \
    PH13(d, 1, sB3, af1, 0, accV,                                               \
         { STGB13(B3g, (kn) + 32, sB3 + (1 - (d)) * 8192 + 4096); },            \
         asm volatile("s_waitcnt vmcnt(5)" ::: "memory"));                      \
}

    // prologue: tile 0 -> buf 0 (8 loads), then force S0,S1 done (keep 5)
    STGA13(0, sA); STGB13(B1g, 0, sB1);
    STGA13(32, sA + 8192); STGB13(B1g, 32, sB1 + 4096);
    STGB13(B3g, 0, sB3); STGB13(B3g, 32, sB3 + 4096);
    asm volatile("s_waitcnt vmcnt(5)" ::: "memory");
    __builtin_amdgcn_s_barrier();

    int kt = 0;
#pragma unroll 1
    for (; kt + 2 < KT; kt += 2) {
        TILE13(0, (kt + 1) * 64);
        TILE13(1, (kt + 2) * 64);
    }
    TILE13(0, (kt + 1) * 64);            // tile KT-2, stages tile KT-1 -> buf1
    // final tile (d=1), no staging; drain 2 -> 1 -> 0
    PH13(1, 0, sB1, af0, 1, accU, , asm volatile("s_waitcnt vmcnt(2)" ::: "memory"));
    PH13(1, 1, sB1, af1, 1, accU, , asm volatile("s_waitcnt vmcnt(1)" ::: "memory"));
    PH13(1, 0, sB3, af0, 0, accV, , asm volatile("s_waitcnt vmcnt(0)" ::: "memory"));
    PH13(1, 1, sB3, af1, 0, accV, , );

    // Epilogue: silu(U)*V -> LDS bf16 [256][136] -> full-line stores
    __syncthreads();
    bf16_t* Ct = smem;
#pragma unroll
    for (int i = 0; i < 4; ++i)
#pragma unroll
        for (int j = 0; j < 4; ++j) {
            int r = wm * 64 + i * 16 + quad * 4;
            int c = wn * 64 + j * 16 + l16;
#pragma unroll
            for (int t = 0; t < 4; ++t) {
                float u = accU[i][j][t];
                float v = accV[i][j][t];
                float h = (u / (1.f + __expf(-u))) * v;
                Ct[(r + t) * 136 + c] = (bf16_t)h;
            }
        }
    __syncthreads();
#pragma unroll
    for (int s = 0; s < 8; ++s) {
        int r = s * 32 + (tid >> 4);
        int cb = (tid & 15) * 8;
        bf16x8 v = *(const bf16x8*)(Ct + r * 136 + cb);
        *(bf16x8*)(Hh + (size_t)(row0 + r) * N + col0 + cb) = v;
    }
#undef TILE13
#undef PH13
#undef STGA13
#undef STGB13
}

// ---------- GEMM2: Out = Hh * W2 ----------
// Tile 256(M) x 256(N), BK=64, 8 waves = 2M x 4N, per-wave 128x64.
__global__ __launch_bounds__(512, 2) void gemm2k(const bf16_t* __restrict__ Hh,
                                                 const bf16_t* __restrict__ W2t,
                                                 float* __restrict__ Outc,
                                                 int row_base) {
    const int K = 2048, N = 1024, KT = 32;
    int nwg = gridDim.x, id = blockIdx.x;
    if ((nwg & 7) == 0) id = (id & 7) * (nwg >> 3) + (id >> 3);
    int nbx = nwg >> 2;                    // 4 col-blocks
    int bx = id % nbx, by = id / nbx;
    int row0 = bx * 256, col0 = by * 256;
    int seg = ((row_base + row0) & 2047) >> 9;
    const bf16_t* Ag = Hh + (size_t)row0 * K;
    const bf16_t* Bg = W2t + ((size_t)seg * N + col0) * K;

    __shared__ __align__(16) bf16_t smem[65536];     // 128 KB
    bf16_t* sA = smem;             // [d:2][ks:2][8192]
    bf16_t* sB = smem + 32768;     // [d:2][ks:2][8192]

    int tid = threadIdx.x, lane = tid & 63, w = tid >> 6;
    int wm = w >> 2, wn = w & 3;           // 2M x 4N
    int quad = lane >> 4, l16 = lane & 15;

    int r0 = 2 * (tid >> 3) + ((tid >> 2) & 1);
    int c0 = (tid & 3) ^ ((tid >> 3) & 3);
    int offG  = r0 * K + c0 * 8;
    int offG2 = offG + 128 * K;

    int sigRd = ((l16 & 1) << 2) | (quad ^ ((l16 >> 1) & 3));
    int rdA = (wm * 64 + (l16 >> 1)) * 64 + sigRd * 8;  // + mq*2048 + i*512
    int rdB = (wn * 32 + (l16 >> 1)) * 64 + sigRd * 8;  // + j*512

    f32x4 acc[8][4];
    f32x4 z = {0.f, 0.f, 0.f, 0.f};
#pragma unroll
    for (int i = 0; i < 8; ++i)
#pragma unroll
        for (int j = 0; j < 4; ++j) acc[i][j] = z;

    bf16x8 bfr[4];

#define STG2KA(k0, dst) { gload16(Ag + (k0) + offG, (dst) + tid * 8); \
                          gload16(Ag + (k0) + offG2, (dst) + 4096 + tid * 8); }
#define STG2KB(k0, dst) { gload16(Bg + (k0) + offG, (dst) + tid * 8); \
                          gload16(Bg + (k0) + offG2, (dst) + 4096 + tid * 8); }

#define PH2K(d, mq, ks, RDB, STAGE, WAITA) {                                    \
    PH_FENCE;                                                                   \
    bf16x8 af_[4];                                                              \
    _Pragma("unroll")                                                           \
    for (int i_ = 0; i_ < 4; ++i_)                                              \
        af_[i_] = *(const bf16x8*)(sA + (d) * 16384 + (ks) * 8192 + rdA + (mq) * 2048 + i_ * 512); \
    if (RDB) {                                                                  \
        _Pragma("unroll")                                                       \
        for (int j_ = 0; j_ < 4; ++j_)                                          \
            bfr[j_] = *(const bf16x8*)(sB + (d) * 16384 + (ks) * 8192 + rdB + j_ * 512); \
    }                                                                           \
    STAGE;                                                                      \
    WAITA;                                                                      \
    __builtin_amdgcn_s_barrier();                                               \
    asm volatile("s_waitcnt lgkmcnt(0)" ::: "memory");                          \
    __builtin_amdgcn_sched_barrier(0);                                          \
    __builtin_amdgcn_s_setprio(1);                                              \
    _Pragma("unroll")                                                           \
    for (int i_ = 0; i_ < 4; ++i_)                                              \
        _Pragma("unroll")                                                       \
        for (int j_ = 0; j_ < 4; ++j_)                                          \
            acc[(mq) * 4 + i_][j_] = MFMA16(af_[i_], bfr[j_], acc[(mq) * 4 + i_][j_]); \
    __builtin_amdgcn_s_setprio(0);                                              \
    __builtin_amdgcn_s_barrier();                                               \
}

// Stages per tile: S0=A-k0(2) S1=B-k0(2) S2=A-k1(2) S3=B-k1(2).
// Needs: p0:{S0,S1} p2:{S2,S3}. Counted waits: C1=4, C3=4.
#define TILE2K(d, kn) {                                                         \
    PH2K(d, 0, 0, 1, STG2KA(kn, sA + (1 - (d)) * 16384), );                     \
    PH2K(d, 1, 0, 0, STG2KB(kn, sB + (1 - (d)) * 16384),                        \
         asm volatile("s_waitcnt vmcnt(4)" ::: "memory"));                      \
    PH2K(d, 0, 1, 1, STG2KA((kn) + 32, sA + (1 - (d)) * 16384 + 8192), );       \
    PH2K(d, 1, 1, 0, STG2KB((kn) + 32, sB + (1 - (d)) * 16384 + 8192),          \
         asm volatile("s_waitcnt vmcnt(4)" ::: "memory"));                      \
}

    STG2KA(0, sA); STG2KB(0, sB);
    STG2KA(32, sA + 8192); STG2KB(32, sB + 8192);
    asm volatile("s_waitcnt vmcnt(4)" ::: "memory");
    __builtin_amdgcn_s_barrier();

    int kt = 0;
#pragma unroll 1
    for (; kt + 2 < KT; kt += 2) {
        TILE2K(0, (kt + 1) * 64);
        TILE2K(1, (kt + 2) * 64);
    }
    TILE2K(0, (kt + 1) * 64);
    PH2K(1, 0, 0, 1, , );
    PH2K(1, 1, 0, 0, , asm volatile("s_waitcnt vmcnt(0)" ::: "memory"));
    PH2K(1, 0, 1, 1, , );
    PH2K(1, 1, 1, 0, , );

    // Epilogue: 4 x 64-row passes through f32 LDS [64][260], 1KB/row stores
    __syncthreads();
    float* smemf = (float*)smem;
    for (int pass = 0; pass < 4; ++pass) {
        if (pass) __syncthreads();
        if (wm == (pass >> 1)) {
            int mq = pass & 1;
#pragma unroll
            for (int i = 0; i < 4; ++i)
#pragma unroll
                for (int j = 0; j < 4; ++j) {
                    int r = i * 16 + quad * 4;
                    int c = wn * 64 + j * 16 + l16;
#pragma unroll
                    for (int t = 0; t < 4; ++t)
                        smemf[(r + t) * 260 + c] = acc[mq * 4 + i][j][t];
                }
        }
        __syncthreads();
#pragma unroll
        for (int s = 0; s < 8; ++s) {
            int r = s * 8 + w;
            f32x4 v = *(const f32x4*)(smemf + r * 260 + lane * 4);
            *(f32x4*)(Outc + (size_t)(row0 + pass * 64 + r) * N + col0 + lane * 4) = v;
        }
    }
#undef TILE2K
#undef PH2K
#undef STG2KA
#undef STG2KB
}

extern "C" void kernel_launch(void* const* d_in, const int* in_sizes, int n_in,
                              void* d_out, int out_size, void* d_ws, size_t ws_size,
                              hipStream_t stream) {
    const float* x  = (const float*)d_in[0];   // fp32 [8,2048,1024]
    const float* w1 = (const float*)d_in[1];   // fp32 [4,1024,2048]
    const float* w3 = (const float*)d_in[2];   // fp32 [4,1024,2048]
    const float* w2 = (const float*)d_in[3];   // fp32 [4,2048,1024]
    float* out = (float*)d_out;                // fp32 [8,2048,1024]

    const size_t WSEG = (size_t)4 * 1024 * 2048;
    bf16_t* w1t = (bf16_t*)d_ws;
    bf16_t* w3t = w1t + WSEG;
    bf16_t* w2t = w3t + WSEG;
    bf16_t* dyn = w2t + WSEG;

    transcvt64<<<dim3(32, 16, 4), 256, 0, stream>>>(w1, (unsigned short*)w1t, 1024, 2048);
    transcvt64<<<dim3(32, 16, 4), 256, 0, stream>>>(w3, (unsigned short*)w3t, 1024, 2048);
    transcvt64<<<dim3(16, 32, 4), 256, 0, stream>>>(w2, (unsigned short*)w2t, 2048, 1024);

    const int TOTAL_ROWS = 16384;
    size_t wbytes = 3 * WSEG * sizeof(bf16_t);
    size_t avail = (ws_size > wbytes) ? ws_size - wbytes : 0;
    int chunk_rows = TOTAL_ROWS;
    while (chunk_rows > 256 && (size_t)chunk_rows * 6144 > avail)
        chunk_rows >>= 1;

    for (int rb = 0; rb < TOTAL_ROWS; rb += chunk_rows) {
        bf16_t* Xb = dyn;
        bf16_t* Hh = dyn + (size_t)chunk_rows * 1024;
        cvtx<<<chunk_rows / 2, 256, 0, stream>>>(x + (size_t)rb * 1024, Xb);
        gemm13<<<(chunk_rows / 256) * 16, 512, 0, stream>>>(Xb, w1t, w3t, Hh, rb);
        gemm2k<<<(chunk_rows / 256) * 4, 512, 0, stream>>>(Hh, w2t, out + (size_t)rb * 1024, rb);
    }
}

// Round 2
// 397.682 us; speedup vs baseline: 1.0671x; 1.0199x over previous
//
#include <hip/hip_runtime.h>
#include <hip/hip_bf16.h>

typedef __bf16 bf16_t;
typedef __attribute__((ext_vector_type(8))) __bf16 bf16x8;
typedef __attribute__((ext_vector_type(4))) float f32x4;
typedef __attribute__((ext_vector_type(8))) unsigned short ushort8v;

#define MFMA16(a, b, c) __builtin_amdgcn_mfma_f32_16x16x32_bf16((a), (b), (c), 0, 0, 0)

__device__ __forceinline__ unsigned short f2bf(float f) {
    bf16_t b = (bf16_t)f;
    return __builtin_bit_cast(unsigned short, b);
}

__device__ __forceinline__ void gload16(const void* g, void* l) {
    __builtin_amdgcn_global_load_lds(
        (const __attribute__((address_space(1))) void*)g,
        (__attribute__((address_space(3))) void*)l,
        16, 0, 0);
}

// ---------- fp32 -> bf16 elementwise convert (for X) ----------
__global__ __launch_bounds__(256) void cvtx(const float* __restrict__ src,
                                            bf16_t* __restrict__ dst) {
    size_t i = ((size_t)blockIdx.x * 256 + threadIdx.x) * 8;
    f32x4 v0 = *(const f32x4*)(src + i);
    f32x4 v1 = *(const f32x4*)(src + i + 4);
    bf16x8 o;
    o[0] = (bf16_t)v0[0]; o[1] = (bf16_t)v0[1];
    o[2] = (bf16_t)v0[2]; o[3] = (bf16_t)v0[3];
    o[4] = (bf16_t)v1[0]; o[5] = (bf16_t)v1[1];
    o[6] = (bf16_t)v1[2]; o[7] = (bf16_t)v1[3];
    *(bf16x8*)(dst + i) = o;
}

// ---------- batched 64x64 transpose + fp32->bf16 convert ----------
// Store side now emits 16B/lane (ushort8): 8 consecutive lanes cover one
// 128B column run. LDS tile [64][66]: read banks (r + oc>>1)&31 -> 2-way max.
__global__ __launch_bounds__(256) void transcvt64(const float* __restrict__ src,
                                                  unsigned short* __restrict__ dst,
                                                  int R, int C) {
    __shared__ __align__(16) unsigned short tile[64][66];
    size_t off = (size_t)blockIdx.z * R * C;
    const float* s = src + off;
    unsigned short* d = dst + off;
    int tr = blockIdx.y * 64, tc = blockIdx.x * 64;
    int tid = threadIdx.x;
    int lr = tid >> 4;
    int lc = (tid & 15) * 4;
#pragma unroll
    for (int p = 0; p < 4; ++p) {
        int r = p * 16 + lr;
        f32x4 v = *(const f32x4*)(s + (size_t)(tr + r) * C + tc + lc);
        tile[r][lc + 0] = f2bf(v[0]); tile[r][lc + 1] = f2bf(v[1]);
        tile[r][lc + 2] = f2bf(v[2]); tile[r][lc + 3] = f2bf(v[3]);
    }
    __syncthreads();
#pragma unroll
    for (int q = 0; q < 2; ++q) {
        int item = q * 256 + tid;
        int oc = item >> 3;            // column 0..63
        int rb = (item & 7) * 8;       // row octet
        ushort8v v;
#pragma unroll
        for (int t = 0; t < 8; ++t) v[t] = tile[rb + t][oc];
        *(ushort8v*)(d + (size_t)(tc + oc) * R + tr + rb) = v;
    }
}

// =====================================================================
// Ring-buffered 8-phase GEMMs.
// LDS = 4 ring slots x 32KB (one K=32 half-tile each). While computing
// half h, stage half h+3; ONE counted vmcnt per half (forces h+1, issued
// ~5 phases = ~2000 cyc earlier). vmcnt never drains to 0 in main loop.
// Staging swizzle per 8KB sub-stage (128 rows x 32k): line L holds rows
// {2L,2L+1} x 4 chunks, slot sig: row=2L+(sig>>2), chunk=(sig&3)^(L&3).
// Frag read (row,quad): sig=((row&1)<<2)|(quad^((row>>1)&3)) -> b128,
// conflict-free. global_load_lds dest linear; permutation on global src.
// =====================================================================

#define PH_FENCE { __builtin_amdgcn_sched_barrier(0); asm volatile("" ::: "memory"); }
#define LGKM0 { asm volatile("s_waitcnt lgkmcnt(0)" ::: "memory"); __builtin_amdgcn_sched_barrier(0); }

// ---------- GEMM1 fused: Hh = silu(X*W1) * (X*W3) ----------
// Tile 256(M) x 128(N), 8 waves = 4M x 2N, per-wave 64x64 dual (U,V).
// Ring slot: A 16KB (256rx32k) | B1 8KB (128rx32k) | B3 8KB.
__global__ __launch_bounds__(512, 2) void gemm13(const bf16_t* __restrict__ Xb,
                                                 const bf16_t* __restrict__ W1t,
                                                 const bf16_t* __restrict__ W3t,
                                                 bf16_t* __restrict__ Hh,
                                                 int row_base) {
    const int K = 1024, N = 2048;
    int nwg = gridDim.x, id = blockIdx.x;
    if ((nwg & 7) == 0) id = (id & 7) * (nwg >> 3) + (id >> 3);  // XCD swizzle
    int nbx = nwg >> 4;
    int bx = id % nbx, by = id / nbx;      // col-major: co-resident share W-panels
    int row0 = bx * 256, col0 = by * 128;
    int seg = ((row_base + row0) & 2047) >> 9;
    const bf16_t* Ag  = Xb + (size_t)row0 * K;
    const bf16_t* B1g = W1t + ((size_t)seg * N + col0) * K;
    const bf16_t* B3g = W3t + ((size_t)seg * N + col0) * K;

    __shared__ __align__(16) bf16_t smem[65536];     // 4 x 16384-elem slots

    int tid = threadIdx.x, lane = tid & 63, w = tid >> 6;
    int wm = w >> 1, wn = w & 1;
    int quad = lane >> 4, l16 = lane & 15;

    int r0 = 2 * (tid >> 3) + ((tid >> 2) & 1);
    int c0 = (tid & 3) ^ ((tid >> 3) & 3);
    int offG  = r0 * K + c0 * 8;
    int offG2 = offG + 128 * K;

    int sigRd = ((l16 & 1) << 2) | (quad ^ ((l16 >> 1) & 3));
    int rdA = (wm * 32 + (l16 >> 1)) * 64 + sigRd * 8;   // + i*512
    int rdB = (wn * 32 + (l16 >> 1)) * 64 + sigRd * 8;   // + j*512

    f32x4 accU[4][4], accV[4][4];
    f32x4 z = {0.f, 0.f, 0.f, 0.f};
#pragma unroll
    for (int i = 0; i < 4; ++i)
#pragma unroll
        for (int j = 0; j < 4; ++j) { accU[i][j] = z; accV[i][j] = z; }

    bf16x8 af[4], bfr[4];

#define STG13(slot, hh) { bf16_t* d_ = smem + (slot) * 16384; const int kg_ = (hh) * 32; \
    gload16(Ag + kg_ + offG,  d_ + tid * 8); \
    gload16(Ag + kg_ + offG2, d_ + 4096 + tid * 8); \
    gload16(B1g + kg_ + offG, d_ + 8192 + tid * 8); \
    gload16(B3g + kg_ + offG, d_ + 12288 + tid * 8); }

#define HALF13(slot, STG, WAIT) {                                               \
    PH_FENCE;                                                                   \
    { const bf16_t* sa_ = smem + (slot) * 16384;                                \
      _Pragma("unroll")                                                         \
      for (int i_ = 0; i_ < 4; ++i_)                                            \
          af[i_] = *(const bf16x8*)(sa_ + rdA + i_ * 512);                      \
      _Pragma("unroll")                                                         \
      for (int j_ = 0; j_ < 4; ++j_)                                            \
          bfr[j_] = *(const bf16x8*)(sa_ + 8192 + rdB + j_ * 512); }            \
    STG;                                                                        \
    __builtin_amdgcn_s_barrier();                                               \
    LGKM0;                                                                      \
    __builtin_amdgcn_s_setprio(1);                                              \
    _Pragma("unroll")                                                           \
    for (int i_ = 0; i_ < 4; ++i_)                                              \
        _Pragma("unroll")                                                       \
        for (int j_ = 0; j_ < 4; ++j_)                                          \
            accU[i_][j_] = MFMA16(af[i_], bfr[j_], accU[i_][j_]);               \
    __builtin_amdgcn_s_setprio(0);                                              \
    __builtin_amdgcn_s_barrier();                                               \
    PH_FENCE;                                                                   \
    { const bf16_t* sb_ = smem + (slot) * 16384 + 12288;                        \
      _Pragma("unroll")                                                         \
      for (int j_ = 0; j_ < 4; ++j_)                                            \
          bfr[j_] = *(const bf16x8*)(sb_ + rdB + j_ * 512); }                   \
    WAIT;                                                                       \
    __builtin_amdgcn_s_barrier();                                               \
    LGKM0;                                                                      \
    __builtin_amdgcn_s_setprio(1);                                              \
    _Pragma("unroll")                                                           \
    for (int i_ = 0; i_ < 4; ++i_)                                              \
        _Pragma("unroll")                                                       \
        for (int j_ = 0; j_ < 4; ++j_)                                          \
            accV[i_][j_] = MFMA16(af[i_], bfr[j_], accV[i_][j_]);               \
    __builtin_amdgcn_s_setprio(0);                                              \
    __builtin_amdgcn_s_barrier(); }

#define W8_13 asm volatile("s_waitcnt vmcnt(8)" ::: "memory")

    // prologue: halves 0..2 in flight (12 loads); force half 0, keep 8
    STG13(0, 0); STG13(1, 1); STG13(2, 2);
    W8_13;
    __builtin_amdgcn_s_barrier();

#pragma unroll 1
    for (int h = 0; h < 28; h += 4) {           // halves 0..27, stage 3..30
        HALF13(0, STG13(3, h + 3), W8_13);
        HALF13(1, STG13(0, h + 4), W8_13);
        HALF13(2, STG13(1, h + 5), W8_13);
        HALF13(3, STG13(2, h + 6), W8_13);
    }
    HALF13(0, STG13(3, 31), W8_13);             // half 28, stage 31
    HALF13(1, , asm volatile("s_waitcnt vmcnt(4)" ::: "memory"));   // half 29
    HALF13(2, , asm volatile("s_waitcnt vmcnt(0)" ::: "memory"));   // half 30
    HALF13(3, , );                                                  // half 31

    // Epilogue: silu(U)*V -> LDS bf16 [256][136] -> full-line stores
    __syncthreads();
    bf16_t* Ct = smem;
#pragma unroll
    for (int i = 0; i < 4; ++i)
#pragma unroll
        for (int j = 0; j < 4; ++j) {
            int r = wm * 64 + i * 16 + quad * 4;
            int c = wn * 64 + j * 16 + l16;
#pragma unroll
            for (int t = 0; t < 4; ++t) {
                float u = accU[i][j][t];
                float v = accV[i][j][t];
                float h = (u / (1.f + __expf(-u))) * v;
                Ct[(r + t) * 136 + c] = (bf16_t)h;
            }
        }
    __syncthreads();
#pragma unroll
    for (int s = 0; s < 8; ++s) {
        int r = s * 32 + (tid >> 4);
        int cb = (tid & 15) * 8;
        bf16x8 v = *(const bf16x8*)(Ct + r * 136 + cb);
        *(bf16x8*)(Hh + (size_t)(row0 + r) * N + col0 + cb) = v;
    }
#undef HALF13
#undef STG13
#undef W8_13
}

// ---------- GEMM2: Out = Hh * W2 ----------
// Tile 256(M) x 256(N), 8 waves = 2M x 4N, per-wave 128x64.
// Ring slot: A 16KB (256rx32k) | B 16KB (256rx32k).
__global__ __launch_bounds__(512, 2) void gemm2k(const bf16_t* __restrict__ Hh,
                                                 const bf16_t* __restrict__ W2t,
                                                 float* __restrict__ Outc,
                                                 int row_base) {
    const int K = 2048, N = 1024;
    int nwg = gridDim.x, id = blockIdx.x;
    if ((nwg & 7) == 0) id = (id & 7) * (nwg >> 3) + (id >> 3);
    int nbx = nwg >> 2;
    int bx = id % nbx, by = id / nbx;
    int row0 = bx * 256, col0 = by * 256;
    int seg = ((row_base + row0) & 2047) >> 9;
    const bf16_t* Ag = Hh + (size_t)row0 * K;
    const bf16_t* Bg = W2t + ((size_t)seg * N + col0) * K;

    __shared__ __align__(16) bf16_t smem[65536];

    int tid = threadIdx.x, lane = tid & 63, w = tid >> 6;
    int wm = w >> 2, wn = w & 3;
    int quad = lane >> 4, l16 = lane & 15;

    int r0 = 2 * (tid >> 3) + ((tid >> 2) & 1);
    int c0 = (tid & 3) ^ ((tid >> 3) & 3);
    int offG  = r0 * K + c0 * 8;
    int offG2 = offG + 128 * K;

    int sigRd = ((l16 & 1) << 2) | (quad ^ ((l16 >> 1) & 3));
    int rdA = (wm * 64 + (l16 >> 1)) * 64 + sigRd * 8;   // + mq*2048 + i*512
    int rdB = (wn * 32 + (l16 >> 1)) * 64 + sigRd * 8;   // + j*512

    f32x4 acc[8][4];
    f32x4 z = {0.f, 0.f, 0.f, 0.f};
#pragma unroll
    for (int i = 0; i < 8; ++i)
#pragma unroll
        for (int j = 0; j < 4; ++j) acc[i][j] = z;

    bf16x8 af[4], bfr[4];

#define STG2(slot, hh) { bf16_t* d_ = smem + (slot) * 16384; const int kg_ = (hh) * 32; \
    gload16(Ag + kg_ + offG,  d_ + tid * 8); \
    gload16(Ag + kg_ + offG2, d_ + 4096 + tid * 8); \
    gload16(Bg + kg_ + offG,  d_ + 8192 + tid * 8); \
    gload16(Bg + kg_ + offG2, d_ + 12288 + tid * 8); }

#define HALF2(slot, STG, WAIT) {                                                \
    PH_FENCE;                                                                   \
    { const bf16_t* s_ = smem + (slot) * 16384;                                 \
      _Pragma("unroll")                                                         \
      for (int i_ = 0; i_ < 4; ++i_)                                            \
          af[i_] = *(const bf16x8*)(s_ + rdA + i_ * 512);                       \
      _Pragma("unroll")                                                         \
      for (int j_ = 0; j_ < 4; ++j_)                                            \
          bfr[j_] = *(const bf16x8*)(s_ + 8192 + rdB + j_ * 512); }             \
    STG;                                                                        \
    __builtin_amdgcn_s_barrier();                                               \
    LGKM0;                                                                      \
    __builtin_amdgcn_s_setprio(1);                                              \
    _Pragma("unroll")                                                           \
    for (int i_ = 0; i_ < 4; ++i_)                                              \
        _Pragma("unroll")                                                       \
        for (int j_ = 0; j_ < 4; ++j_)                                          \
            acc[i_][j_] = MFMA16(af[i_], bfr[j_], acc[i_][j_]);                 \
    __builtin_amdgcn_s_setprio(0);                                              \
    __builtin_amdgcn_s_barrier();                                               \
    PH_FENCE;                                                                   \
    { const bf16_t* s_ = smem + (slot) * 16384;                                 \
      _Pragma("unroll")                                                         \
      for (int i_ = 0; i_ < 4; ++i_)                                            \
          af[i_] = *(const bf16x8*)(s_ + 2048 + rdA + i_ * 512); }              \
    WAIT;                                                                       \
    __builtin_amdgcn_s_barrier();                                               \
    LGKM0;                                                                      \
    __builtin_amdgcn_s_setprio(1);                                              \
    _Pragma("unroll")                                                           \
    for (int i_ = 0; i_ < 4; ++i_)                                              \
        _Pragma("unroll")                                                       \
        for (int j_ = 0; j_ < 4; ++j_)                                          \
            acc[4 + i_][j_] = MFMA16(af[i_], bfr[j_], acc[4 + i_][j_]);         \
    __builtin_amdgcn_s_setprio(0);                                              \
    __builtin_amdgcn_s_barrier(); }

#define W8_2 asm volatile("s_waitcnt vmcnt(8)" ::: "memory")

    STG2(0, 0); STG2(1, 1); STG2(2, 2);
    W8_2;
    __builtin_amdgcn_s_barrier();

#pragma unroll 1
    for (int h = 0; h < 60; h += 4) {           // halves 0..59, stage 3..62
        HALF2(0, STG2(3, h + 3), W8_2);
        HALF2(1, STG2(0, h + 4), W8_2);
        HALF2(2, STG2(1, h + 5), W8_2);
        HALF2(3, STG2(2, h + 6), W8_2);
    }
    HALF2(0, STG2(3, 63), W8_2);                // half 60, stage 63
    HALF2(1, , asm volatile("s_waitcnt vmcnt(4)" ::: "memory"));    // half 61
    HALF2(2, , asm volatile("s_waitcnt vmcnt(0)" ::: "memory"));    // half 62
    HALF2(3, , );                                                   // half 63

    // Epilogue: 4 x 64-row passes through f32 LDS [64][260], 1KB/row stores
    __syncthreads();
    float* smemf = (float*)smem;
    for (int pass = 0; pass < 4; ++pass) {
        if (pass) __syncthreads();
        if (wm == (pass >> 1)) {
            int mq = pass & 1;
#pragma unroll
            for (int i = 0; i < 4; ++i)
#pragma unroll
                for (int j = 0; j < 4; ++j) {
                    int r = i * 16 + quad * 4;
                    int c = wn * 64 + j * 16 + l16;
#pragma unroll
                    for (int t = 0; t < 4; ++t)
                        smemf[(r + t) * 260 + c] = acc[mq * 4 + i][j][t];
                }
        }
        __syncthreads();
#pragma unroll
        for (int s = 0; s < 8; ++s) {
            int r = s * 8 + w;
            f32x4 v = *(const f32x4*)(smemf + r * 260 + lane * 4);
            *(f32x4*)(Outc + (size_t)(row0 + pass * 64 + r) * N + col0 + lane * 4) = v;
        }
    }
#undef HALF2
#undef STG2
#undef W8_2
}

extern "C" void kernel_launch(void* const* d_in, const int* in_sizes, int n_in,
                              void* d_out, int out_size, void* d_ws, size_t ws_size,
                              hipStream_t stream) {
    const float* x  = (const float*)d_in[0];   // fp32 [8,2048,1024]
    const float* w1 = (const float*)d_in[1];   // fp32 [4,1024,2048]
    const float* w3 = (const float*)d_in[2];   // fp32 [4,1024,2048]
    const float* w2 = (const float*)d_in[3];   // fp32 [4,2048,1024]
    float* out = (float*)d_out;                // fp32 [8,2048,1024]

    const size_t WSEG = (size_t)4 * 1024 * 2048;
    bf16_t* w1t = (bf16_t*)d_ws;
    bf16_t* w3t = w1t + WSEG;
    bf16_t* w2t = w3t + WSEG;
    bf16_t* dyn = w2t + WSEG;

    transcvt64<<<dim3(32, 16, 4), 256, 0, stream>>>(w1, (unsigned short*)w1t, 1024, 2048);
    transcvt64<<<dim3(32, 16, 4), 256, 0, stream>>>(w3, (unsigned short*)w3t, 1024, 2048);
    transcvt64<<<dim3(16, 32, 4), 256, 0, stream>>>(w2, (unsigned short*)w2t, 2048, 1024);

    const int TOTAL_ROWS = 16384;
    size_t wbytes = 3 * WSEG * sizeof(bf16_t);
    size_t avail = (ws_size > wbytes) ? ws_size - wbytes : 0;
    int chunk_rows = TOTAL_ROWS;
    while (chunk_rows > 256 && (size_t)chunk_rows * 6144 > avail)
        chunk_rows >>= 1;

    for (int rb = 0; rb < TOTAL_ROWS; rb += chunk_rows) {
        bf16_t* Xb = dyn;
        bf16_t* Hh = dyn + (size_t)chunk_rows * 1024;
        cvtx<<<chunk_rows / 2, 256, 0, stream>>>(x + (size_t)rb * 1024, Xb);
        gemm13<<<(chunk_rows / 256) * 16, 512, 0, stream>>>(Xb, w1t, w3t, Hh, rb);
        gemm2k<<<(chunk_rows / 256) * 4, 512, 0, stream>>>(Hh, w2t, out + (size_t)rb * 1024, rb);
    }
}